// Round 9
// baseline (765.084 us; speedup 1.0000x reference)
//
#include <hip/hip_runtime.h>
#include <hip/hip_bf16.h>

#define NNODE 100000
#define EDG   500000
#define DD    128
#define FF    64
#define NCLS  5

// ws layout (ushort units). Weights bf16 ROW-MAJOR (A-operand of transposed
// GEMMs: D^T[m=outfeat][n=edge] = W[m][k] * ACT[n][k]).
#define OFF_W1   0                       // [128][64]
#define OFF_W2   8192                    // [128][128]
#define OFF_W3   24576
#define OFF_WCR  40960
#define OFF_WCL  57344
#define OFF_P0   73728
#define OFF_P1   90112
#define OFF_HU   106496                  // [NNODE][128] bf16
#define OFF_HV   (106496 + NNODE * DD)
#define PREP_TOT 106496

#define NODE_GRID 1024
#define EDGE_GRID 1024

typedef __attribute__((ext_vector_type(8))) short short8;
typedef __attribute__((ext_vector_type(4))) float f32x4;

union U4 { uint4 v; ushort s[8]; };

__device__ __forceinline__ float bf2f(ushort u) {
  return __uint_as_float(((unsigned int)u) << 16);
}
__device__ __forceinline__ ushort f2bf(float f) {
  unsigned int u = __float_as_uint(f);
  u += 0x7FFF + ((u >> 16) & 1);
  return (ushort)(u >> 16);
}
__device__ __forceinline__ ushort2 pk2(float a, float b) {
  __hip_bfloat162 t = __float22bfloat162_rn(make_float2(a, b));
  return *(ushort2*)&t;
}
__device__ __forceinline__ ushort4 pk4(float a, float b, float c, float d) {
  ushort2 lo = pk2(a, b), hi = pk2(c, d);
  ushort4 o; o.x = lo.x; o.y = lo.y; o.z = hi.x; o.w = hi.y; return o;
}

// XOR-swizzled LDS addressing (rows = 128 ushorts = 256 B; 16B granule index
// XORed with row&7). col%4==0 required.
__device__ __forceinline__ int sw(int row, int col) {
  return row * 128 + ((((col >> 3) ^ (row & 7)) << 3) | (col & 7));
}

__device__ __forceinline__ void zacc(f32x4 a[2][4]) {
#pragma unroll
  for (int i = 0; i < 2; ++i)
#pragma unroll
    for (int j = 0; j < 4; ++j)
      a[i][j] = (f32x4){0.f, 0.f, 0.f, 0.f};
}

// Transposed GEMM: wave owns feats [m0,m0+32) x all 64 edges.
// A: weights from global (row-major, L2-hot). B: acts from LDS.
// NOTE (R6 post-mortem): register-hoisting the weight A-frags spilled
// (WRITE_SIZE 9.7->212 MB, 3.6x HBM traffic, dur +40%). L2-hot global
// loads are the right source for weights at this occupancy.
__device__ __forceinline__ void gemm_T(const ushort* act,
                                       const ushort* __restrict__ W, int K,
                                       int ksteps, f32x4 acc[2][4],
                                       int m0, int l15, int q) {
  for (int ks = 0; ks < ksteps; ++ks) {
    const int ko = ks * 32 + q * 8;
    short8 a0 = *(const short8*)(W + (m0 + l15) * K + ko);
    short8 a1 = *(const short8*)(W + (m0 + 16 + l15) * K + ko);
#pragma unroll
    for (int nt = 0; nt < 4; ++nt) {
      short8 b = *(const short8*)&act[sw(nt * 16 + l15, ko)];
      acc[0][nt] = __builtin_amdgcn_mfma_f32_16x16x32_bf16(a0, b, acc[0][nt], 0, 0, 0);
      acc[1][nt] = __builtin_amdgcn_mfma_f32_16x16x32_bf16(a1, b, acc[1][nt], 0, 0, 0);
    }
  }
}

// D^T C-layout: lane = edge nt*16+l15, 4 contiguous feats m0+mt*16+q*4+r.
__device__ __forceinline__ void store_T(ushort* dst, f32x4 acc[2][4],
                                        const float* __restrict__ bias, int relu,
                                        int m0, int l15, int q) {
#pragma unroll
  for (int mt = 0; mt < 2; ++mt) {
    const int feat = m0 + mt * 16 + q * 4;
    float4 bv = bias ? *(const float4*)(bias + feat) : make_float4(0.f, 0.f, 0.f, 0.f);
#pragma unroll
    for (int nt = 0; nt < 4; ++nt) {
      const int edge = nt * 16 + l15;
      float v0 = acc[mt][nt][0] + bv.x, v1 = acc[mt][nt][1] + bv.y;
      float v2 = acc[mt][nt][2] + bv.z, v3 = acc[mt][nt][3] + bv.w;
      if (relu) {
        v0 = fmaxf(v0, 0.f); v1 = fmaxf(v1, 0.f);
        v2 = fmaxf(v2, 0.f); v3 = fmaxf(v3, 0.f);
      }
      *(ushort4*)&dst[sw(edge, feat)] = pk4(v0, v1, v2, v3);
    }
  }
}

// ---------------- prep: bf16 row-major weight copies ----------------------
__global__ void __launch_bounds__(256) prep_kernel(
    const float* __restrict__ W1, const float* __restrict__ W2,
    const float* __restrict__ W3, const float* __restrict__ W_comb,
    const float* __restrict__ P, ushort* __restrict__ ws) {
  int idx = blockIdx.x * 256 + threadIdx.x;
  if (idx >= PREP_TOT) return;
  float val;
  if (idx < 8192) {
    val = W1[idx];
  } else {
    int r = idx - 8192, m = r >> 14, rr = r & 16383;
    switch (m) {
      case 0:  val = W2[rr]; break;
      case 1:  val = W3[rr]; break;
      case 2:  { int n = rr >> 7, k = rr & 127; val = W_comb[n * 256 + 128 + k]; } break;
      case 3:  { int n = rr >> 7, k = rr & 127; val = W_comb[n * 256 + k]; } break;
      case 4:  val = P[rr]; break;
      default: val = P[16384 + rr]; break;
    }
  }
  ws[idx] = f2bf(val);
}

// ---------------- node kernel: hu/hv = h @ Wcl^T --------------------------
// Persistent grid-stride blocks; next tile's 128B/thread of h prefetched
// into registers under the GEMM. 2 barriers per tile. No weight hoist
// (R6: hoists spilled); Wcl loads are L2-hot gemm_T.
__global__ void __launch_bounds__(256, 4) node_kernel(
    const float* __restrict__ h_src, const float* __restrict__ h_dst,
    ushort* __restrict__ ws) {
  __shared__ ushort BUF[2][64][128];
  ushort* A = &BUF[0][0][0];
  ushort* B = &BUF[1][0][0];
  const int NT = (NNODE + 63) / 64;
  const int TIL = 2 * NT;
  const int tid = threadIdx.x;
  const int lane = tid & 63, l15 = lane & 15, q = lane >> 4;
  const int m0 = (tid >> 6) * 32;
  const int srow = tid >> 2, part = tid & 3;

  // prologue: first tile's input rows in registers
  float4 xr[8];
  {
    const int t0 = blockIdx.x;          // NODE_GRID < NT, always h_src here
    const float* h = (t0 < NT) ? h_src : h_dst;
    int r = ((t0 < NT) ? t0 : t0 - NT) * 64 + srow;
    if (r >= NNODE) r = NNODE - 1;
    const float4* src = (const float4*)(h + (long)r * DD) + part * 8;
#pragma unroll
    for (int c = 0; c < 8; ++c) xr[c] = src[c];
  }

  for (int t = blockIdx.x; t < TIL; t += NODE_GRID) {
    // stage xr -> A (bf16)
#pragma unroll
    for (int c = 0; c < 4; ++c) {
      float4 v0 = xr[c * 2], v1 = xr[c * 2 + 1];
      U4 o;
      *(ushort4*)&o.s[0] = pk4(v0.x, v0.y, v0.z, v0.w);
      *(ushort4*)&o.s[4] = pk4(v1.x, v1.y, v1.z, v1.w);
      *(uint4*)&A[sw(srow, part * 32 + c * 8)] = o.v;
    }
    __syncthreads();                                  // 1
    // prefetch next tile (HBM latency hidden under GEMM + stores)
    {
      int tn = t + NODE_GRID;
      if (tn < TIL) {
        const float* h = (tn < NT) ? h_src : h_dst;
        int r = ((tn < NT) ? tn : tn - NT) * 64 + srow;
        if (r >= NNODE) r = NNODE - 1;
        const float4* src = (const float4*)(h + (long)r * DD) + part * 8;
#pragma unroll
        for (int c = 0; c < 8; ++c) xr[c] = src[c];
      }
    }
    f32x4 acc[2][4];
    zacc(acc);
    gemm_T(A, ws + OFF_WCL, 128, 4, acc, m0, l15, q);
    store_T(B, acc, nullptr, 0, m0, l15, q);
    __syncthreads();                                  // 2
    {
      const int r0 = ((t < NT) ? t : t - NT) * 64;
      ushort* op = ws + ((t < NT) ? OFF_HU : OFF_HV);
      if (r0 + srow < NNODE) {
        uint4* d = (uint4*)(op + (long)(r0 + srow) * DD + part * 32);
#pragma unroll
        for (int i = 0; i < 4; ++i)
          d[i] = *(const uint4*)&B[sw(srow, part * 32 + i * 8)];
      }
    }
    // next iter: stage writes A (gemm reads of A fenced by barrier 2);
    // own out-reads of B precede own next barrier 1, store_T(B) is after it.
  }
}

// ---------------- fused edge kernel: persistent, 64 edges/tile ------------
// 7 barriers per tile (was 9): U built in-place over ec during the V phase,
// and T-GEMM + U.T dot fused into one phase (dot reads per-wave tacc regs
// and A which was written before barrier 6).
// Weights via gemm_T (L2-hot; R6: reg-hoisting them spilled).
// efeats/idx prefetched one tile ahead; hu/hv gathers issued 2 phases early.
__global__ void __launch_bounds__(256, 4) edge_kernel(
    const float* __restrict__ efeats, const int* __restrict__ u_idx,
    const int* __restrict__ v_idx, const float* __restrict__ b1,
    const float* __restrict__ b2, const float* __restrict__ b3,
    const float* __restrict__ W_cb, const ushort* __restrict__ ws,
    float* __restrict__ out) {
  __shared__ ushort BUF[2][64][128];
  __shared__ float OB[64][2];
  ushort* A = &BUF[0][0][0];
  ushort* B = &BUF[1][0][0];

  const int tid = threadIdx.x;
  const int lane = tid & 63;
  const int l15 = lane & 15, q = lane >> 4;
  const int m0 = (tid >> 6) * 32;
  const int srow = tid >> 2, part = tid & 3;
  const int TIL = (EDG + 63) / 64;

  float wcb[2 * NCLS];
#pragma unroll
  for (int i = 0; i < 2 * NCLS; ++i) wcb[i] = W_cb[i];

  // prologue: first tile's efeats + endpoints
  float4 xr[4];
  int ui, vi;
  {
    long g = (long)blockIdx.x * 64 + srow;
    if (g >= EDG) g = EDG - 1;
    ui = u_idx[g]; vi = v_idx[g];
    const float4* src = (const float4*)(efeats + g * FF) + part * 4;
#pragma unroll
    for (int c = 0; c < 4; ++c) xr[c] = src[c];
  }

  for (long t = blockIdx.x; t < TIL; t += EDGE_GRID) {
    const long e0 = t * 64;
    // stage X -> A   [64 edges][64 feats]
#pragma unroll
    for (int c = 0; c < 2; ++c) {
      float4 v0 = xr[c * 2], v1 = xr[c * 2 + 1];
      U4 o;
      *(ushort4*)&o.s[0] = pk4(v0.x, v0.y, v0.z, v0.w);
      *(ushort4*)&o.s[4] = pk4(v1.x, v1.y, v1.z, v1.w);
      *(uint4*)&A[sw(srow, part * 16 + c * 8)] = o.v;
    }
    __syncthreads();                                    // 1
    // prefetch next tile's efeats + idx (~6 phases of cover)
    int un = ui, vn = vi;
    {
      long tn = t + EDGE_GRID;
      if (tn < TIL) {
        long g = tn * 64 + srow;
        if (g >= EDG) g = EDG - 1;
        un = u_idx[g]; vn = v_idx[g];
        const float4* src = (const float4*)(efeats + g * FF) + part * 4;
#pragma unroll
        for (int c = 0; c < 4; ++c) xr[c] = src[c];
      }
    }
    f32x4 acc[2][4];
    // e1 = relu(X@W1^T+b1): A -> B
    zacc(acc); gemm_T(A, ws + OFF_W1, 64, 2, acc, m0, l15, q);
    store_T(B, acc, b1, 1, m0, l15, q);
    __syncthreads();                                    // 2
    // e2: B -> A
    zacc(acc); gemm_T(B, ws + OFF_W2, 128, 4, acc, m0, l15, q);
    store_T(A, acc, b2, 1, m0, l15, q);
    __syncthreads();                                    // 3
    // issue hu/hv gathers (LLC-latency, consumed at UV phase, >=2 phases away)
    uint4 hvp[4], hup[4];
    {
      const uint4* hv = (const uint4*)(ws + OFF_HV + (long)vi * DD + part * 32);
      const uint4* hu = (const uint4*)(ws + OFF_HU + (long)ui * DD + part * 32);
#pragma unroll
      for (int c = 0; c < 4; ++c) hvp[c] = hv[c];
#pragma unroll
      for (int c = 0; c < 4; ++c) hup[c] = hu[c];
    }
    // e3: A -> B
    zacc(acc); gemm_T(A, ws + OFF_W3, 128, 4, acc, m0, l15, q);
    store_T(B, acc, b3, 0, m0, l15, q);
    __syncthreads();                                    // 4
    // ec = e3@Wcr^T: B -> A
    zacc(acc); gemm_T(B, ws + OFF_WCR, 128, 4, acc, m0, l15, q);
    store_T(A, acc, nullptr, 0, m0, l15, q);
    __syncthreads();                                    // 5
    // UV: V = hv + ec -> B ; U = hu + ec -> A (in place, same-thread slots)
#pragma unroll
    for (int c = 0; c < 4; ++c) {
      U4 e; e.v = *(const uint4*)&A[sw(srow, part * 32 + c * 8)];
      U4 hv_; hv_.v = hvp[c];
      U4 hu_; hu_.v = hup[c];
      U4 vo, uo;
#pragma unroll
      for (int j = 0; j < 8; j += 2) {
        float ea = bf2f(e.s[j]), eb = bf2f(e.s[j + 1]);
        ushort2 pv = pk2(bf2f(hv_.s[j]) + ea, bf2f(hv_.s[j + 1]) + eb);
        ushort2 pu = pk2(bf2f(hu_.s[j]) + ea, bf2f(hu_.s[j + 1]) + eb);
        vo.s[j] = pv.x; vo.s[j + 1] = pv.y;
        uo.s[j] = pu.x; uo.s[j + 1] = pu.y;
      }
      *(uint4*)&B[sw(srow, part * 32 + c * 8)] = vo.v;
      *(uint4*)&A[sw(srow, part * 32 + c * 8)] = uo.v;
    }
    if (tid < 128) OB[tid >> 1][tid & 1] = 0.f;
    __syncthreads();                                    // 6
    // T_b = V @ P_b^T (bases fused to share B-frags) ...
    f32x4 tacc[2][2][4];
    zacc(tacc[0]); zacc(tacc[1]);
    for (int ks = 0; ks < 4; ++ks) {
      const int ko = ks * 32 + q * 8;
      short8 a00 = *(const short8*)(ws + OFF_P0 + (m0 + l15) * 128 + ko);
      short8 a01 = *(const short8*)(ws + OFF_P0 + (m0 + 16 + l15) * 128 + ko);
      short8 a10 = *(const short8*)(ws + OFF_P1 + (m0 + l15) * 128 + ko);
      short8 a11 = *(const short8*)(ws + OFF_P1 + (m0 + 16 + l15) * 128 + ko);
#pragma unroll
      for (int nt = 0; nt < 4; ++nt) {
        short8 b = *(const short8*)&B[sw(nt * 16 + l15, ko)];
        tacc[0][0][nt] = __builtin_amdgcn_mfma_f32_16x16x32_bf16(a00, b, tacc[0][0][nt], 0, 0, 0);
        tacc[0][1][nt] = __builtin_amdgcn_mfma_f32_16x16x32_bf16(a01, b, tacc[0][1][nt], 0, 0, 0);
        tacc[1][0][nt] = __builtin_amdgcn_mfma_f32_16x16x32_bf16(a10, b, tacc[1][0][nt], 0, 0, 0);
        tacc[1][1][nt] = __builtin_amdgcn_mfma_f32_16x16x32_bf16(a11, b, tacc[1][1][nt], 0, 0, 0);
      }
    }
    // ... fused dot: out_b[edge] = sum_feat U[edge][feat] * T_b[edge][feat]
    // (U in A, written before barrier 6; tacc is per-wave registers)
#pragma unroll
    for (int nt = 0; nt < 4; ++nt) {
      const int edge = nt * 16 + l15;
      float pb0 = 0.f, pb1 = 0.f;
#pragma unroll
      for (int mt = 0; mt < 2; ++mt) {
        ushort4 u4 = *(const ushort4*)&A[sw(edge, m0 + mt * 16 + q * 4)];
        float uf;
        uf = bf2f(u4.x); pb0 += tacc[0][mt][nt][0] * uf; pb1 += tacc[1][mt][nt][0] * uf;
        uf = bf2f(u4.y); pb0 += tacc[0][mt][nt][1] * uf; pb1 += tacc[1][mt][nt][1] * uf;
        uf = bf2f(u4.z); pb0 += tacc[0][mt][nt][2] * uf; pb1 += tacc[1][mt][nt][2] * uf;
        uf = bf2f(u4.w); pb0 += tacc[0][mt][nt][3] * uf; pb1 += tacc[1][mt][nt][3] * uf;
      }
      pb0 += __shfl_xor(pb0, 16, 64); pb0 += __shfl_xor(pb0, 32, 64);
      pb1 += __shfl_xor(pb1, 16, 64); pb1 += __shfl_xor(pb1, 32, 64);
      if (q == 0) {
        atomicAdd(&OB[edge][0], pb0);
        atomicAdd(&OB[edge][1], pb1);
      }
    }
    __syncthreads();                                    // 7
    for (int tt = tid; tt < 64 * NCLS; tt += 256) {
      int r = tt / NCLS, c = tt % NCLS;
      long erow = e0 + r;
      if (erow < EDG)
        out[erow * NCLS + c] = OB[r][0] * wcb[c * 2] + OB[r][1] * wcb[c * 2 + 1];
    }
    // next iter's stage(A) is fenced by barrier 7 (dot's A-reads precede it);
    // next OB zeroing happens after next barrier 5, past everyone's out-reads.
    ui = un; vi = vn;
  }
}

extern "C" void kernel_launch(void* const* d_in, const int* in_sizes, int n_in,
                              void* d_out, int out_size, void* d_ws,
                              size_t ws_size, hipStream_t stream) {
  const float* h_src  = (const float*)d_in[0];
  const float* h_dst  = (const float*)d_in[1];
  const float* efeats = (const float*)d_in[2];
  const int*   u_idx  = (const int*)d_in[3];
  const int*   v_idx  = (const int*)d_in[4];
  const float* W1     = (const float*)d_in[5];
  const float* b1     = (const float*)d_in[6];
  const float* W2     = (const float*)d_in[7];
  const float* b2     = (const float*)d_in[8];
  const float* W3     = (const float*)d_in[9];
  const float* b3     = (const float*)d_in[10];
  const float* W_comb = (const float*)d_in[11];
  const float* P      = (const float*)d_in[12];
  const float* W_cb   = (const float*)d_in[13];
  ushort* ws = (ushort*)d_ws;
  float* out = (float*)d_out;

  prep_kernel<<<(PREP_TOT + 255) / 256, 256, 0, stream>>>(W1, W2, W3, W_comb, P, ws);
  node_kernel<<<NODE_GRID, 256, 0, stream>>>(h_src, h_dst, ws);
  edge_kernel<<<EDGE_GRID, 256, 0, stream>>>(efeats, u_idx, v_idx,
                                             b1, b2, b3, W_cb, ws, out);
}

// Round 10
// 472.717 us; speedup vs baseline: 1.6185x; 1.6185x over previous
//
#include <hip/hip_runtime.h>
#include <hip/hip_bf16.h>

#define NNODE 100000
#define EDG   500000
#define DD    128
#define FF    64
#define NCLS  5

// ws layout (ushort units). Weights bf16 ROW-MAJOR (A-operand of transposed
// GEMMs: D^T[m=outfeat][n=edge] = W[m][k] * ACT[n][k]).
#define OFF_W1   0                       // [128][64]
#define OFF_W2   8192                    // [128][128]
#define OFF_W3   24576
#define OFF_WCR  40960
#define OFF_WCL  57344
#define OFF_P0   73728
#define OFF_P1   90112
#define OFF_HU   106496                  // [NNODE][128] bf16
#define OFF_HV   (106496 + NNODE * DD)
#define PREP_TOT 106496

typedef __attribute__((ext_vector_type(8))) short short8;
typedef __attribute__((ext_vector_type(4))) float f32x4;

union U4 { uint4 v; ushort s[8]; };

__device__ __forceinline__ float bf2f(ushort u) {
  return __uint_as_float(((unsigned int)u) << 16);
}
__device__ __forceinline__ ushort f2bf(float f) {
  unsigned int u = __float_as_uint(f);
  u += 0x7FFF + ((u >> 16) & 1);
  return (ushort)(u >> 16);
}
__device__ __forceinline__ ushort2 pk2(float a, float b) {
  __hip_bfloat162 t = __float22bfloat162_rn(make_float2(a, b));
  return *(ushort2*)&t;
}
__device__ __forceinline__ ushort4 pk4(float a, float b, float c, float d) {
  ushort2 lo = pk2(a, b), hi = pk2(c, d);
  ushort4 o; o.x = lo.x; o.y = lo.y; o.z = hi.x; o.w = hi.y; return o;
}

// XOR-swizzled LDS addressing (rows = 128 ushorts = 256 B; 16B granule index
// XORed with row&7). col%4==0 required.
__device__ __forceinline__ int sw(int row, int col) {
  return row * 128 + ((((col >> 3) ^ (row & 7)) << 3) | (col & 7));
}

// R6/R9 lessons: (1) reg-hoisting weights spilled (WRITE 212 MB); (2) deep
// cross-tile reg prefetch got demoted to scratch (WRITE 360 MB, 1.48 GB
// traffic) even at VGPR_Count=64. Register budget at occupancy cannot hold
// prefetch state on top of MFMA accumulators. This version instead buys
// latency hiding with THIN WAVES: 512 thr / 8 waves x 16 feats per tile
// (was 256 / 4 x 32). Same LDS -> same blocks/CU by LDS, 2x waves, and
// per-wave registers HALVE (acc 16, tacc 32). Schedule = proven R0.

__device__ __forceinline__ void zacc1(f32x4 a[4]) {
#pragma unroll
  for (int j = 0; j < 4; ++j) a[j] = (f32x4){0.f, 0.f, 0.f, 0.f};
}

// Thin transposed GEMM: wave owns feats [m0,m0+16) x all 64 edges.
// A: weights from global (row-major, L2-hot). B: acts from LDS.
__device__ __forceinline__ void gemm_T1(const ushort* act,
                                        const ushort* __restrict__ W, int K,
                                        int ksteps, f32x4 acc[4],
                                        int m0, int l15, int q) {
  for (int ks = 0; ks < ksteps; ++ks) {
    const int ko = ks * 32 + q * 8;
    short8 a0 = *(const short8*)(W + (m0 + l15) * K + ko);
#pragma unroll
    for (int nt = 0; nt < 4; ++nt) {
      short8 b = *(const short8*)&act[sw(nt * 16 + l15, ko)];
      acc[nt] = __builtin_amdgcn_mfma_f32_16x16x32_bf16(a0, b, acc[nt], 0, 0, 0);
    }
  }
}

// D^T C-layout: lane = edge nt*16+l15, 4 contiguous feats m0+q*4+r.
__device__ __forceinline__ void store_T1(ushort* dst, f32x4 acc[4],
                                         const float* __restrict__ bias, int relu,
                                         int m0, int l15, int q) {
  const int feat = m0 + q * 4;
  float4 bv = bias ? *(const float4*)(bias + feat) : make_float4(0.f, 0.f, 0.f, 0.f);
#pragma unroll
  for (int nt = 0; nt < 4; ++nt) {
    const int edge = nt * 16 + l15;
    float v0 = acc[nt][0] + bv.x, v1 = acc[nt][1] + bv.y;
    float v2 = acc[nt][2] + bv.z, v3 = acc[nt][3] + bv.w;
    if (relu) {
      v0 = fmaxf(v0, 0.f); v1 = fmaxf(v1, 0.f);
      v2 = fmaxf(v2, 0.f); v3 = fmaxf(v3, 0.f);
    }
    *(ushort4*)&dst[sw(edge, feat)] = pk4(v0, v1, v2, v3);
  }
}

// ---------------- prep: bf16 row-major weight copies ----------------------
__global__ void __launch_bounds__(256) prep_kernel(
    const float* __restrict__ W1, const float* __restrict__ W2,
    const float* __restrict__ W3, const float* __restrict__ W_comb,
    const float* __restrict__ P, ushort* __restrict__ ws) {
  int idx = blockIdx.x * 256 + threadIdx.x;
  if (idx >= PREP_TOT) return;
  float val;
  if (idx < 8192) {
    val = W1[idx];
  } else {
    int r = idx - 8192, m = r >> 14, rr = r & 16383;
    switch (m) {
      case 0:  val = W2[rr]; break;
      case 1:  val = W3[rr]; break;
      case 2:  { int n = rr >> 7, k = rr & 127; val = W_comb[n * 256 + 128 + k]; } break;
      case 3:  { int n = rr >> 7, k = rr & 127; val = W_comb[n * 256 + k]; } break;
      case 4:  val = P[rr]; break;
      default: val = P[16384 + rr]; break;
    }
  }
  ws[idx] = f2bf(val);
}

// ---------------- node kernel: hu/hv = h @ Wcl^T --------------------------
// 64 rows / 512 threads (8 thin waves x 16 feats) / ~33 KB LDS.
__global__ void __launch_bounds__(512, 6) node_kernel(
    const float* __restrict__ h_src, const float* __restrict__ h_dst,
    ushort* __restrict__ ws) {
  __shared__ ushort BUF[2][64][128];
  ushort* A = &BUF[0][0][0];
  ushort* B = &BUF[1][0][0];
  const int NT = (NNODE + 63) / 64;
  const int tid = threadIdx.x;
  const int lane = tid & 63, l15 = lane & 15, q = lane >> 4;
  const int m0 = (tid >> 6) * 16;        // 8 waves x 16 feats
  const int bb = blockIdx.x;
  const float* h = (bb < NT) ? h_src : h_dst;
  ushort* op = ws + ((bb < NT) ? OFF_HU : OFF_HV);
  const int r0 = ((bb < NT) ? bb : bb - NT) * 64;
  const int srow = tid >> 3, part = tid & 7;   // 8 threads per 128-float row
  int row = r0 + srow; if (row >= NNODE) row = NNODE - 1;
  {
    // part covers 16 floats = 4 float4 -> 2 bf16 granules
    const float4* src = (const float4*)(h + (long)row * DD) + part * 4;
#pragma unroll
    for (int c = 0; c < 2; ++c) {
      float4 v0 = src[c * 2], v1 = src[c * 2 + 1];
      U4 o;
      *(ushort4*)&o.s[0] = pk4(v0.x, v0.y, v0.z, v0.w);
      *(ushort4*)&o.s[4] = pk4(v1.x, v1.y, v1.z, v1.w);
      *(uint4*)&A[sw(srow, part * 16 + c * 8)] = o.v;
    }
  }
  __syncthreads();
  f32x4 acc[4];
  zacc1(acc);
  gemm_T1(A, ws + OFF_WCL, 128, 4, acc, m0, l15, q);
  store_T1(B, acc, nullptr, 0, m0, l15, q);
  __syncthreads();
  if (r0 + srow < NNODE) {
    uint4* d = (uint4*)(op + (long)(r0 + srow) * DD + part * 16);
#pragma unroll
    for (int i = 0; i < 2; ++i)
      d[i] = *(const uint4*)&B[sw(srow, part * 16 + i * 8)];
  }
}

// ---------------- fused edge kernel: 64 edges / 8 thin waves --------------
// Exact R0 9-barrier schedule (proven 250 us, no scratch), thin-wave split.
__global__ void __launch_bounds__(512, 6) edge_kernel(
    const float* __restrict__ efeats, const int* __restrict__ u_idx,
    const int* __restrict__ v_idx, const float* __restrict__ b1,
    const float* __restrict__ b2, const float* __restrict__ b3,
    const float* __restrict__ W_cb, const ushort* __restrict__ ws,
    float* __restrict__ out) {
  __shared__ ushort BUF[2][64][128];
  __shared__ float OB[64][2];
  ushort* A = &BUF[0][0][0];
  ushort* B = &BUF[1][0][0];

  const int tid = threadIdx.x;
  const int lane = tid & 63;
  const int l15 = lane & 15, q = lane >> 4;
  const int m0 = (tid >> 6) * 16;        // 8 waves x 16 feats
  const long e0 = (long)blockIdx.x * 64;

  const int srow = tid >> 3, part = tid & 7;
  long grow = e0 + srow; if (grow >= EDG) grow = EDG - 1;
  const int vi = v_idx[grow], ui = u_idx[grow];

  // stage X -> A   [64 edges][64 feats]; part covers 8 floats -> 1 granule
  {
    const float4* src = (const float4*)(efeats + grow * FF) + part * 2;
    float4 v0 = src[0], v1 = src[1];
    U4 o;
    *(ushort4*)&o.s[0] = pk4(v0.x, v0.y, v0.z, v0.w);
    *(ushort4*)&o.s[4] = pk4(v1.x, v1.y, v1.z, v1.w);
    *(uint4*)&A[sw(srow, part * 8)] = o.v;
  }
  __syncthreads();                                    // 1

  f32x4 acc[4];
  // e1 = relu(X@W1^T+b1): A -> B
  zacc1(acc); gemm_T1(A, ws + OFF_W1, 64, 2, acc, m0, l15, q);
  store_T1(B, acc, b1, 1, m0, l15, q);
  __syncthreads();                                    // 2
  // e2: B -> A
  zacc1(acc); gemm_T1(B, ws + OFF_W2, 128, 4, acc, m0, l15, q);
  store_T1(A, acc, b2, 1, m0, l15, q);
  __syncthreads();                                    // 3
  // e3: A -> B
  zacc1(acc); gemm_T1(A, ws + OFF_W3, 128, 4, acc, m0, l15, q);
  store_T1(B, acc, b3, 0, m0, l15, q);
  __syncthreads();                                    // 4

  // hv prefetch (covered by ec GEMM); 2 granules per thread
  uint4 hvp[2];
  {
    const uint4* hp = (const uint4*)(ws + OFF_HV + (long)vi * DD) + part * 2;
    hvp[0] = hp[0]; hvp[1] = hp[1];
  }
  // ec = e3@Wcr^T: B -> A   (A = ec, live until U-build)
  zacc1(acc); gemm_T1(B, ws + OFF_WCR, 128, 4, acc, m0, l15, q);
  store_T1(A, acc, nullptr, 0, m0, l15, q);
  __syncthreads();                                    // 5

  // V = hv + ec: A -> B ; zero OB
  {
#pragma unroll
    for (int c = 0; c < 2; ++c) {
      U4 a; a.v = hvp[c];
      U4 e; e.v = *(const uint4*)&A[sw(srow, part * 16 + c * 8)];
      U4 o;
#pragma unroll
      for (int j = 0; j < 8; j += 2) {
        ushort2 p = pk2(bf2f(a.s[j]) + bf2f(e.s[j]),
                        bf2f(a.s[j + 1]) + bf2f(e.s[j + 1]));
        o.s[j] = p.x; o.s[j + 1] = p.y;
      }
      *(uint4*)&B[sw(srow, part * 16 + c * 8)] = o.v;
    }
    if (tid < 128) OB[tid >> 1][tid & 1] = 0.f;
  }
  __syncthreads();                                    // 6

  // hu prefetch (covered by P GEMMs)
  uint4 hup[2];
  {
    const uint4* hp = (const uint4*)(ws + OFF_HU + (long)ui * DD) + part * 2;
    hup[0] = hp[0]; hup[1] = hp[1];
  }

  // T_b = V @ P_b^T (bases fused to share B-frags): read B
  f32x4 tacc[2][4];
  zacc1(tacc[0]); zacc1(tacc[1]);
  for (int ks = 0; ks < 4; ++ks) {
    const int ko = ks * 32 + q * 8;
    short8 a0 = *(const short8*)(ws + OFF_P0 + (m0 + l15) * 128 + ko);
    short8 a1 = *(const short8*)(ws + OFF_P1 + (m0 + l15) * 128 + ko);
#pragma unroll
    for (int nt = 0; nt < 4; ++nt) {
      short8 b = *(const short8*)&B[sw(nt * 16 + l15, ko)];
      tacc[0][nt] = __builtin_amdgcn_mfma_f32_16x16x32_bf16(a0, b, tacc[0][nt], 0, 0, 0);
      tacc[1][nt] = __builtin_amdgcn_mfma_f32_16x16x32_bf16(a1, b, tacc[1][nt], 0, 0, 0);
    }
  }
  __syncthreads();                                    // 7 (B reads done)

  // U = hu + ec: A -> B
  {
#pragma unroll
    for (int c = 0; c < 2; ++c) {
      U4 a; a.v = hup[c];
      U4 e; e.v = *(const uint4*)&A[sw(srow, part * 16 + c * 8)];
      U4 o;
#pragma unroll
      for (int j = 0; j < 8; j += 2) {
        ushort2 p = pk2(bf2f(a.s[j]) + bf2f(e.s[j]),
                        bf2f(a.s[j + 1]) + bf2f(e.s[j + 1]));
        o.s[j] = p.x; o.s[j + 1] = p.y;
      }
      *(uint4*)&B[sw(srow, part * 16 + c * 8)] = o.v;
    }
  }
  __syncthreads();                                    // 8

  // out_b[edge] = sum_feat U[edge][feat] * T_b[edge][feat]
#pragma unroll
  for (int nt = 0; nt < 4; ++nt) {
    const int edge = nt * 16 + l15;
    float pb0 = 0.f, pb1 = 0.f;
    ushort4 u4 = *(const ushort4*)&B[sw(edge, m0 + q * 4)];
    float uf;
    uf = bf2f(u4.x); pb0 += tacc[0][nt][0] * uf; pb1 += tacc[1][nt][0] * uf;
    uf = bf2f(u4.y); pb0 += tacc[0][nt][1] * uf; pb1 += tacc[1][nt][1] * uf;
    uf = bf2f(u4.z); pb0 += tacc[0][nt][2] * uf; pb1 += tacc[1][nt][2] * uf;
    uf = bf2f(u4.w); pb0 += tacc[0][nt][3] * uf; pb1 += tacc[1][nt][3] * uf;
    pb0 += __shfl_xor(pb0, 16, 64); pb0 += __shfl_xor(pb0, 32, 64);
    pb1 += __shfl_xor(pb1, 16, 64); pb1 += __shfl_xor(pb1, 32, 64);
    if (q == 0) {
      atomicAdd(&OB[edge][0], pb0);
      atomicAdd(&OB[edge][1], pb1);
    }
  }
  __syncthreads();                                    // 9

  if (tid < 64 * NCLS) {
    int r = tid / NCLS, c = tid % NCLS;
    long erow = e0 + r;
    if (erow < EDG) {
      out[erow * NCLS + c] = OB[r][0] * W_cb[c * 2] + OB[r][1] * W_cb[c * 2 + 1];
    }
  }
}

extern "C" void kernel_launch(void* const* d_in, const int* in_sizes, int n_in,
                              void* d_out, int out_size, void* d_ws,
                              size_t ws_size, hipStream_t stream) {
  const float* h_src  = (const float*)d_in[0];
  const float* h_dst  = (const float*)d_in[1];
  const float* efeats = (const float*)d_in[2];
  const int*   u_idx  = (const int*)d_in[3];
  const int*   v_idx  = (const int*)d_in[4];
  const float* W1     = (const float*)d_in[5];
  const float* b1     = (const float*)d_in[6];
  const float* W2     = (const float*)d_in[7];
  const float* b2     = (const float*)d_in[8];
  const float* W3     = (const float*)d_in[9];
  const float* b3     = (const float*)d_in[10];
  const float* W_comb = (const float*)d_in[11];
  const float* P      = (const float*)d_in[12];
  const float* W_cb   = (const float*)d_in[13];
  ushort* ws = (ushort*)d_ws;
  float* out = (float*)d_out;

  prep_kernel<<<(PREP_TOT + 255) / 256, 256, 0, stream>>>(W1, W2, W3, W_comb, P, ws);
  node_kernel<<<2 * ((NNODE + 63) / 64), 512, 0, stream>>>(h_src, h_dst, ws);
  edge_kernel<<<(EDG + 63) / 64, 512, 0, stream>>>(efeats, u_idx, v_idx,
                                                   b1, b2, b3, W_cb, ws, out);
}

// Round 11
// 450.258 us; speedup vs baseline: 1.6992x; 1.0499x over previous
//
#include <hip/hip_runtime.h>
#include <hip/hip_bf16.h>

#define NNODE 100000
#define EDG   500000
#define DD    128
#define FF    64
#define NCLS  5

// ws layout (ushort units). Weights bf16 ROW-MAJOR (A-operand of transposed
// GEMMs: D^T[m=outfeat][n=edge] = W[m][k] * ACT[n][k]).
#define OFF_W1   0                       // [128][64]
#define OFF_W2   8192                    // [128][128]
#define OFF_W3   24576
#define OFF_WCR  40960
#define OFF_WCL  57344
#define OFF_P0   73728
#define OFF_P1   90112
#define OFF_HU   106496                  // [NNODE][128] bf16
#define OFF_HV   (106496 + NNODE * DD)
#define PREP_TOT 106496

typedef __attribute__((ext_vector_type(8))) short short8;
typedef __attribute__((ext_vector_type(4))) float f32x4;

union U4 { uint4 v; ushort s[8]; };

__device__ __forceinline__ float bf2f(ushort u) {
  return __uint_as_float(((unsigned int)u) << 16);
}
__device__ __forceinline__ ushort f2bf(float f) {
  unsigned int u = __float_as_uint(f);
  u += 0x7FFF + ((u >> 16) & 1);
  return (ushort)(u >> 16);
}
__device__ __forceinline__ ushort2 pk2(float a, float b) {
  __hip_bfloat162 t = __float22bfloat162_rn(make_float2(a, b));
  return *(ushort2*)&t;
}
__device__ __forceinline__ ushort4 pk4(float a, float b, float c, float d) {
  ushort2 lo = pk2(a, b), hi = pk2(c, d);
  ushort4 o; o.x = lo.x; o.y = lo.y; o.z = hi.x; o.w = hi.y; return o;
}

// XOR-swizzled LDS addressing (rows = 128 ushorts = 256 B; 16B granule index
// XORed with row&7). col%4==0 required.
__device__ __forceinline__ int sw(int row, int col) {
  return row * 128 + ((((col >> 3) ^ (row & 7)) << 3) | (col & 7));
}

// Ledger: R6 reg-hoisted weights -> spill (WRITE 212 MB). R9 deep reg
// prefetch -> scratch demotion (WRITE 360 MB). R10 thin waves: occupancy
// 42->64.5%, dur UNCHANGED 252 us -> latency/occupancy theory dead; no pipe
// saturated. Invariant = per-tile phase overhead (9 barrier-separated
// phases, weight-load bursts un-hoistable across barriers) x tile count.
// R11: amortize -- 128 edges/tile, half the tiles, half the phase
// boundaries and weight streams per edge. Register profile = R0's proven
// 64-VGPR layout. Schedule = R0's proven 9-barrier schedule.

// Thin transposed GEMM over NT 16-edge tiles: wave owns feats [m0,m0+16).
template <int NT>
__device__ __forceinline__ void gemm_T1(const ushort* act,
                                        const ushort* __restrict__ W, int K,
                                        int ksteps, f32x4 acc[NT],
                                        int m0, int l15, int q) {
  for (int ks = 0; ks < ksteps; ++ks) {
    const int ko = ks * 32 + q * 8;
    short8 a0 = *(const short8*)(W + (m0 + l15) * K + ko);
#pragma unroll
    for (int nt = 0; nt < NT; ++nt) {
      short8 b = *(const short8*)&act[sw(nt * 16 + l15, ko)];
      acc[nt] = __builtin_amdgcn_mfma_f32_16x16x32_bf16(a0, b, acc[nt], 0, 0, 0);
    }
  }
}

template <int NT>
__device__ __forceinline__ void zaccN(f32x4 a[NT]) {
#pragma unroll
  for (int j = 0; j < NT; ++j) a[j] = (f32x4){0.f, 0.f, 0.f, 0.f};
}

// D^T C-layout: lane = edge nt*16+l15, 4 contiguous feats m0+q*4+r.
template <int NT>
__device__ __forceinline__ void store_T1(ushort* dst, f32x4 acc[NT],
                                         const float* __restrict__ bias, int relu,
                                         int m0, int l15, int q) {
  const int feat = m0 + q * 4;
  float4 bv = bias ? *(const float4*)(bias + feat) : make_float4(0.f, 0.f, 0.f, 0.f);
#pragma unroll
  for (int nt = 0; nt < NT; ++nt) {
    const int edge = nt * 16 + l15;
    float v0 = acc[nt][0] + bv.x, v1 = acc[nt][1] + bv.y;
    float v2 = acc[nt][2] + bv.z, v3 = acc[nt][3] + bv.w;
    if (relu) {
      v0 = fmaxf(v0, 0.f); v1 = fmaxf(v1, 0.f);
      v2 = fmaxf(v2, 0.f); v3 = fmaxf(v3, 0.f);
    }
    *(ushort4*)&dst[sw(edge, feat)] = pk4(v0, v1, v2, v3);
  }
}

// ---------------- prep: bf16 row-major weight copies ----------------------
__global__ void __launch_bounds__(256) prep_kernel(
    const float* __restrict__ W1, const float* __restrict__ W2,
    const float* __restrict__ W3, const float* __restrict__ W_comb,
    const float* __restrict__ P, ushort* __restrict__ ws) {
  int idx = blockIdx.x * 256 + threadIdx.x;
  if (idx >= PREP_TOT) return;
  float val;
  if (idx < 8192) {
    val = W1[idx];
  } else {
    int r = idx - 8192, m = r >> 14, rr = r & 16383;
    switch (m) {
      case 0:  val = W2[rr]; break;
      case 1:  val = W3[rr]; break;
      case 2:  { int n = rr >> 7, k = rr & 127; val = W_comb[n * 256 + 128 + k]; } break;
      case 3:  { int n = rr >> 7, k = rr & 127; val = W_comb[n * 256 + k]; } break;
      case 4:  val = P[rr]; break;
      default: val = P[16384 + rr]; break;
    }
  }
  ws[idx] = f2bf(val);
}

// ---------------- node kernel: hu/hv = h @ Wcl^T --------------------------
// 128 rows / 512 threads (8 waves x 16 feats x 8 row-tiles) / ~64 KB LDS.
__global__ void __launch_bounds__(512, 4) node_kernel(
    const float* __restrict__ h_src, const float* __restrict__ h_dst,
    ushort* __restrict__ ws) {
  __shared__ ushort BUF[2][128][128];
  ushort* A = &BUF[0][0][0];
  ushort* B = &BUF[1][0][0];
  const int NTIL = (NNODE + 127) / 128;
  const int tid = threadIdx.x;
  const int lane = tid & 63, l15 = lane & 15, q = lane >> 4;
  const int m0 = (tid >> 6) * 16;              // 8 waves x 16 feats
  const int bb = blockIdx.x;
  const float* h = (bb < NTIL) ? h_src : h_dst;
  ushort* op = ws + ((bb < NTIL) ? OFF_HU : OFF_HV);
  const int r0 = ((bb < NTIL) ? bb : bb - NTIL) * 128;
  const int srow = tid >> 2, part = tid & 3;   // 4 threads per 128-float row
  int row = r0 + srow; if (row >= NNODE) row = NNODE - 1;
  {
    const float4* src = (const float4*)(h + (long)row * DD) + part * 8;
#pragma unroll
    for (int c = 0; c < 4; ++c) {
      float4 v0 = src[c * 2], v1 = src[c * 2 + 1];
      U4 o;
      *(ushort4*)&o.s[0] = pk4(v0.x, v0.y, v0.z, v0.w);
      *(ushort4*)&o.s[4] = pk4(v1.x, v1.y, v1.z, v1.w);
      *(uint4*)&A[sw(srow, part * 32 + c * 8)] = o.v;
    }
  }
  __syncthreads();
  f32x4 acc[8];
  zaccN<8>(acc);
  gemm_T1<8>(A, ws + OFF_WCL, 128, 4, acc, m0, l15, q);
  store_T1<8>(B, acc, nullptr, 0, m0, l15, q);
  __syncthreads();
  if (r0 + srow < NNODE) {
    uint4* d = (uint4*)(op + (long)(r0 + srow) * DD + part * 32);
#pragma unroll
    for (int i = 0; i < 4; ++i)
      d[i] = *(const uint4*)&B[sw(srow, part * 32 + i * 8)];
  }
}

// ---------------- fused edge kernel: 128 edges / 8 waves ------------------
// R0's 9-barrier schedule, 2x edge tile (amortizes phase overhead).
__global__ void __launch_bounds__(512, 4) edge_kernel(
    const float* __restrict__ efeats, const int* __restrict__ u_idx,
    const int* __restrict__ v_idx, const float* __restrict__ b1,
    const float* __restrict__ b2, const float* __restrict__ b3,
    const float* __restrict__ W_cb, const ushort* __restrict__ ws,
    float* __restrict__ out) {
  __shared__ ushort BUF[2][128][128];
  __shared__ float OB[128][2];
  ushort* A = &BUF[0][0][0];
  ushort* B = &BUF[1][0][0];

  const int tid = threadIdx.x;
  const int lane = tid & 63;
  const int l15 = lane & 15, q = lane >> 4;
  const int m0 = (tid >> 6) * 16;              // 8 waves x 16 feats
  const long e0 = (long)blockIdx.x * 128;

  const int srow = tid >> 2, part = tid & 3;   // 4 threads per edge row
  long grow = e0 + srow; if (grow >= EDG) grow = EDG - 1;
  const int vi = v_idx[grow], ui = u_idx[grow];

  // stage X -> A  [128 edges][64 feats]; part covers 16 floats -> 2 granules
  {
    const float4* src = (const float4*)(efeats + grow * FF) + part * 4;
#pragma unroll
    for (int c = 0; c < 2; ++c) {
      float4 v0 = src[c * 2], v1 = src[c * 2 + 1];
      U4 o;
      *(ushort4*)&o.s[0] = pk4(v0.x, v0.y, v0.z, v0.w);
      *(ushort4*)&o.s[4] = pk4(v1.x, v1.y, v1.z, v1.w);
      *(uint4*)&A[sw(srow, part * 16 + c * 8)] = o.v;
    }
  }
  __syncthreads();                                    // 1

  f32x4 acc[8];
  // e1 = relu(X@W1^T+b1): A -> B
  zaccN<8>(acc); gemm_T1<8>(A, ws + OFF_W1, 64, 2, acc, m0, l15, q);
  store_T1<8>(B, acc, b1, 1, m0, l15, q);
  __syncthreads();                                    // 2
  // e2: B -> A
  zaccN<8>(acc); gemm_T1<8>(B, ws + OFF_W2, 128, 4, acc, m0, l15, q);
  store_T1<8>(A, acc, b2, 1, m0, l15, q);
  __syncthreads();                                    // 3
  // e3: A -> B
  zaccN<8>(acc); gemm_T1<8>(A, ws + OFF_W3, 128, 4, acc, m0, l15, q);
  store_T1<8>(B, acc, b3, 0, m0, l15, q);
  __syncthreads();                                    // 4

  // hv prefetch (covered by ec GEMM); 4 granules per thread
  uint4 hvp[4];
  {
    const uint4* hp = (const uint4*)(ws + OFF_HV + (long)vi * DD) + part * 4;
#pragma unroll
    for (int c = 0; c < 4; ++c) hvp[c] = hp[c];
  }
  // ec = e3@Wcr^T: B -> A   (A = ec, live until U-build)
  zaccN<8>(acc); gemm_T1<8>(B, ws + OFF_WCR, 128, 4, acc, m0, l15, q);
  store_T1<8>(A, acc, nullptr, 0, m0, l15, q);
  __syncthreads();                                    // 5

  // V = hv + ec: A -> B ; zero OB
  {
#pragma unroll
    for (int c = 0; c < 4; ++c) {
      U4 a; a.v = hvp[c];
      U4 e; e.v = *(const uint4*)&A[sw(srow, part * 32 + c * 8)];
      U4 o;
#pragma unroll
      for (int j = 0; j < 8; j += 2) {
        ushort2 p = pk2(bf2f(a.s[j]) + bf2f(e.s[j]),
                        bf2f(a.s[j + 1]) + bf2f(e.s[j + 1]));
        o.s[j] = p.x; o.s[j + 1] = p.y;
      }
      *(uint4*)&B[sw(srow, part * 32 + c * 8)] = o.v;
    }
    if (tid < 256) OB[tid >> 1][tid & 1] = 0.f;
  }
  __syncthreads();                                    // 6

  // hu prefetch (covered by P GEMMs)
  uint4 hup[4];
  {
    const uint4* hp = (const uint4*)(ws + OFF_HU + (long)ui * DD) + part * 4;
#pragma unroll
    for (int c = 0; c < 4; ++c) hup[c] = hp[c];
  }

  // T_b = V @ P_b^T (bases fused to share B-frags): read B
  f32x4 tacc[2][8];
  zaccN<8>(tacc[0]); zaccN<8>(tacc[1]);
  for (int ks = 0; ks < 4; ++ks) {
    const int ko = ks * 32 + q * 8;
    short8 a0 = *(const short8*)(ws + OFF_P0 + (m0 + l15) * 128 + ko);
    short8 a1 = *(const short8*)(ws + OFF_P1 + (m0 + l15) * 128 + ko);
#pragma unroll
    for (int nt = 0; nt < 8; ++nt) {
      short8 b = *(const short8*)&B[sw(nt * 16 + l15, ko)];
      tacc[0][nt] = __builtin_amdgcn_mfma_f32_16x16x32_bf16(a0, b, tacc[0][nt], 0, 0, 0);
      tacc[1][nt] = __builtin_amdgcn_mfma_f32_16x16x32_bf16(a1, b, tacc[1][nt], 0, 0, 0);
    }
  }
  __syncthreads();                                    // 7 (B reads done)

  // U = hu + ec: A -> B
  {
#pragma unroll
    for (int c = 0; c < 4; ++c) {
      U4 a; a.v = hup[c];
      U4 e; e.v = *(const uint4*)&A[sw(srow, part * 32 + c * 8)];
      U4 o;
#pragma unroll
      for (int j = 0; j < 8; j += 2) {
        ushort2 p = pk2(bf2f(a.s[j]) + bf2f(e.s[j]),
                        bf2f(a.s[j + 1]) + bf2f(e.s[j + 1]));
        o.s[j] = p.x; o.s[j + 1] = p.y;
      }
      *(uint4*)&B[sw(srow, part * 32 + c * 8)] = o.v;
    }
  }
  __syncthreads();                                    // 8

  // out_b[edge] = sum_feat U[edge][feat] * T_b[edge][feat]
#pragma unroll
  for (int nt = 0; nt < 8; ++nt) {
    const int edge = nt * 16 + l15;
    float pb0 = 0.f, pb1 = 0.f;
    ushort4 u4 = *(const ushort4*)&B[sw(edge, m0 + q * 4)];
    float uf;
    uf = bf2f(u4.x); pb0 += tacc[0][nt][0] * uf; pb1 += tacc[1][nt][0] * uf;
    uf = bf2f(u4.y); pb0 += tacc[0][nt][1] * uf; pb1 += tacc[1][nt][1] * uf;
    uf = bf2f(u4.z); pb0 += tacc[0][nt][2] * uf; pb1 += tacc[1][nt][2] * uf;
    uf = bf2f(u4.w); pb0 += tacc[0][nt][3] * uf; pb1 += tacc[1][nt][3] * uf;
    pb0 += __shfl_xor(pb0, 16, 64); pb0 += __shfl_xor(pb0, 32, 64);
    pb1 += __shfl_xor(pb1, 16, 64); pb1 += __shfl_xor(pb1, 32, 64);
    if (q == 0) {
      atomicAdd(&OB[edge][0], pb0);
      atomicAdd(&OB[edge][1], pb1);
    }
  }
  __syncthreads();                                    // 9

  for (int t = tid; t < 128 * NCLS; t += 512) {
    int r = t / NCLS, c = t % NCLS;
    long erow = e0 + r;
    if (erow < EDG) {
      out[erow * NCLS + c] = OB[r][0] * W_cb[c * 2] + OB[r][1] * W_cb[c * 2 + 1];
    }
  }
}

extern "C" void kernel_launch(void* const* d_in, const int* in_sizes, int n_in,
                              void* d_out, int out_size, void* d_ws,
                              size_t ws_size, hipStream_t stream) {
  const float* h_src  = (const float*)d_in[0];
  const float* h_dst  = (const float*)d_in[1];
  const float* efeats = (const float*)d_in[2];
  const int*   u_idx  = (const int*)d_in[3];
  const int*   v_idx  = (const int*)d_in[4];
  const float* W1     = (const float*)d_in[5];
  const float* b1     = (const float*)d_in[6];
  const float* W2     = (const float*)d_in[7];
  const float* b2     = (const float*)d_in[8];
  const float* W3     = (const float*)d_in[9];
  const float* b3     = (const float*)d_in[10];
  const float* W_comb = (const float*)d_in[11];
  const float* P      = (const float*)d_in[12];
  const float* W_cb   = (const float*)d_in[13];
  ushort* ws = (ushort*)d_ws;
  float* out = (float*)d_out;

  prep_kernel<<<(PREP_TOT + 255) / 256, 256, 0, stream>>>(W1, W2, W3, W_comb, P, ws);
  node_kernel<<<2 * ((NNODE + 127) / 128), 512, 0, stream>>>(h_src, h_dst, ws);
  edge_kernel<<<(EDG + 127) / 128, 512, 0, stream>>>(efeats, u_idx, v_idx,
                                                     b1, b2, b3, W_cb, ws, out);
}